// Round 4
// baseline (9115.665 us; speedup 1.0000x reference)
//
#include <hip/hip_runtime.h>
#include <math.h>

#define NN 100000
#define EE 3200000
#define INF 128
#define OUTF 64
#define ALPHA 0.1f

#define BROWS 128                      // rows per bin
#define NBINS 782                      // ceil(NN/BROWS)
#define CAP 4472                       // per-bin slot capacity (avg 4092, +5.9 sigma)
#define SCHUNK 4096                    // edges sorted per LDS chunk
#define SBLK 16384                     // edges per bin_scatter block
#define NSUM ((NBINS + 3) / 4)         // 196

// ---------------- GEMM: support0 = x @ W  ([N,128]@[128,64]) ----------------
__global__ __launch_bounds__(256) void gemm_kernel(
    const float* __restrict__ x, const float* __restrict__ W, float* __restrict__ out)
{
    __shared__ float Wl[INF * OUTF];  // 32 KB
    for (int idx = threadIdx.x; idx < INF * OUTF; idx += 256) Wl[idx] = W[idx];
    __syncthreads();

    int row = blockIdx.x * 4 + (threadIdx.x >> 6);
    int f = threadIdx.x & 63;
    if (row >= NN) return;
    const float* xr = x + (size_t)row * INF;
    float acc = 0.f;
#pragma unroll
    for (int k = 0; k < INF; k += 4) {
        float4 xv = *reinterpret_cast<const float4*>(xr + k);
        acc += xv.x * Wl[(k + 0) * OUTF + f];
        acc += xv.y * Wl[(k + 1) * OUTF + f];
        acc += xv.z * Wl[(k + 2) * OUTF + f];
        acc += xv.w * Wl[(k + 3) * OUTF + f];
    }
    out[(size_t)row * OUTF + f] = acc;
}

// ------------- binning pass: counting-sort edges into 128-row bins ----------
// Per block: histogram its 16K edges, reserve per-bin global space once
// (runs from successive 4K chunks concatenate -> long contiguous writes),
// then per chunk: LDS counting sort + coalesced run writes.
__global__ __launch_bounds__(256) void bin_scatter(
    const int* __restrict__ rows, const int* __restrict__ cols,
    const float* __restrict__ vals, int* __restrict__ gcur,
    uint2* __restrict__ binned, int nedges)
{
    __shared__ uint2 rec[SCHUNK];      // 32 KB
    __shared__ int hist[NBINS];
    __shared__ int lcur[NBINS];        // per-bin global write cursor (relative)
    __shared__ int hc[NBINS];          // per-chunk counts
    __shared__ int off[NBINS + 1];     // per-chunk exclusive offsets
    __shared__ int cur[NBINS];         // per-chunk placement cursors
    __shared__ int sums[NSUM];

    int tid = threadIdx.x;
    int base = blockIdx.x * SBLK;
    int n = min(SBLK, nedges - base);
    if (n <= 0) return;

    for (int b = tid; b < NBINS; b += 256) hist[b] = 0;
    __syncthreads();
    for (int i = tid; i < n; i += 256) atomicAdd(&hist[rows[base + i] >> 7], 1);
    __syncthreads();
    for (int b = tid; b < NBINS; b += 256) {
        int c = hist[b];
        lcur[b] = c ? atomicAdd(&gcur[b], c) : 0;
    }

    for (int c0 = 0; c0 < n; c0 += SCHUNK) {
        int nc = min(SCHUNK, n - c0);
        __syncthreads();
        for (int b = tid; b < NBINS; b += 256) hc[b] = 0;
        __syncthreads();
        for (int i = tid; i < nc; i += 256)
            atomicAdd(&hc[rows[base + c0 + i] >> 7], 1);
        __syncthreads();
        // exclusive scan hc -> off
        if (tid < NSUM) {
            int s = 0;
#pragma unroll
            for (int k = 0; k < 4; k++) { int b = 4 * tid + k; if (b < NBINS) s += hc[b]; }
            sums[tid] = s;
        }
        __syncthreads();
        if (tid == 0) {
            int acc = 0;
            for (int t = 0; t < NSUM; t++) { int v = sums[t]; sums[t] = acc; acc += v; }
            off[NBINS] = acc;
        }
        __syncthreads();
        if (tid < NSUM) {
            int acc = sums[tid];
#pragma unroll
            for (int k = 0; k < 4; k++) {
                int b = 4 * tid + k;
                if (b < NBINS) { off[b] = acc; cur[b] = acc; acc += hc[b]; }
            }
        }
        __syncthreads();
        // place records sorted-by-bin into rec
        for (int i = tid; i < nc; i += 256) {
            int r = rows[base + c0 + i];
            int cc = cols[base + c0 + i];
            float v = vals[base + c0 + i];
            int b = r >> 7;
            int pos = atomicAdd(&cur[b], 1);
            uint2 q;
            q.x = (unsigned)cc | ((unsigned)(r & (BROWS - 1)) << 17);
            q.y = __float_as_uint(v);
            rec[pos] = q;
        }
        __syncthreads();
        // write runs (consecutive i -> consecutive global dest within a run)
        for (int i = tid; i < nc; i += 256) {
            int lo = 0, hi = NBINS;
            while (hi - lo > 1) { int mid = (lo + hi) >> 1; if (off[mid] <= i) lo = mid; else hi = mid; }
            binned[(size_t)lo * CAP + lcur[lo] + (i - off[lo])] = rec[i];
        }
        __syncthreads();
        for (int b = tid; b < NBINS; b += 256) lcur[b] += hc[b];
    }
}

// ------------- SpMM over bins: LDS dense tile accumulation ------------------
__global__ __launch_bounds__(256) void spmm_bin(
    const uint2* __restrict__ binned, const int* __restrict__ gcur,
    const float* __restrict__ X, float* __restrict__ Y)
{
    __shared__ float tile[BROWS * OUTF];  // 32 KB
    __shared__ uint2 ebuf[256];           // 2 KB edge staging

    int bin = blockIdx.x;
    int tid = threadIdx.x;
    int lane = tid & 63;
    int wv = tid >> 6;

    for (int i = tid; i < BROWS * OUTF; i += 256) tile[i] = 0.f;

    int cnt = gcur[bin];
    const uint2* src = binned + (size_t)bin * CAP;

    for (int b0 = 0; b0 < cnt; b0 += 256) {
        __syncthreads();
        int nb = min(256, cnt - b0);
        if (tid < nb) ebuf[tid] = src[b0 + tid];
        __syncthreads();
        int jend = min(nb, wv * 64 + 64);
#pragma unroll 4
        for (int j = wv * 64; j < jend; j++) {
            uint2 q = ebuf[j];
            int col = q.x & 0x1FFFF;
            int lr = (q.x >> 17) & (BROWS - 1);
            float v = __uint_as_float(q.y);
            float xv = X[(size_t)col * OUTF + lane];
            atomicAdd(&tile[lr * OUTF + lane], v * xv);
        }
    }
    __syncthreads();

    int rbase = bin * BROWS;
    for (int r = wv; r < BROWS; r += 4) {
        int gr = rbase + r;
        if (gr < NN) Y[(size_t)gr * OUTF + lane] = tile[r * OUTF + lane];
    }
}

// ---------------- Fused attention epilogue ----------------------------------
__global__ __launch_bounds__(256) void fuse_kernel(
    const float* __restrict__ hA, const float* __restrict__ hA2, const float* __restrict__ hA3,
    const float* __restrict__ s1, const float* __restrict__ s2, const float* __restrict__ s3,
    const float* __restrict__ a, float* __restrict__ out)
{
    __shared__ float chl[4][6][OUTF];  // 6 KB
    int wid = threadIdx.x >> 6;
    int lane = threadIdx.x & 63;
    int i = blockIdx.x * 4 + wid;
    if (i >= NN) return;

    const float* bufs[6] = {hA, hA2, hA3, s1, s2, s3};

#pragma unroll
    for (int k = 0; k < 6; k++) {
        float v = bufs[k][(size_t)i * OUTF + lane];
        if (k >= 3) v = fabsf(v);
        chl[wid][k][lane] = v;
    }

    float att[6];
    if (i < NN / 2) {
#pragma unroll
        for (int k = 0; k < 6; k++) att[k] = 1.0f / 6.0f;
    } else {
        int m = 2 * i - NN;
        float alo = a[lane];
        float ahi = a[64 + lane];
        float e[6];
#pragma unroll
        for (int k = 0; k < 6; k++) {
            float v0 = bufs[k][(size_t)m * OUTF + lane];
            float v1 = bufs[k][(size_t)(m + 1) * OUTF + lane];
            if (k >= 3) { v0 = fabsf(v0); v1 = fabsf(v1); }
            float p = alo * v0 + ahi * v1;
#pragma unroll
            for (int off = 32; off; off >>= 1) p += __shfl_xor(p, off);
            e[k] = (p > 0.f) ? p : ALPHA * p;
        }
        float mx = e[0];
#pragma unroll
        for (int k = 1; k < 6; k++) mx = fmaxf(mx, e[k]);
        float s = 0.f;
#pragma unroll
        for (int k = 0; k < 6; k++) { att[k] = __expf(e[k] - mx); s += att[k]; }
        float inv = 1.f / s;
#pragma unroll
        for (int k = 0; k < 6; k++) att[k] *= inv;
    }

    if (lane < 6) out[(size_t)NN * OUTF + (size_t)i * 6 + lane] = att[lane];

    float hp = 0.f;
#pragma unroll
    for (int j = 0; j < 6; j++) {
        int g = j * 64 + lane;
        hp += att[j] * chl[wid][g % 6][g / 6];
    }
    out[(size_t)i * OUTF + lane] = hp * (1.0f / 6.0f);
}

extern "C" void kernel_launch(void* const* d_in, const int* in_sizes, int n_in,
                              void* d_out, int out_size, void* d_ws, size_t ws_size,
                              hipStream_t stream)
{
    const float* x = (const float*)d_in[0];
    const float* W = (const float*)d_in[1];
    const float* a = (const float*)d_in[2];
    const int*   A_rows  = (const int*)d_in[3];
    const int*   A_cols  = (const int*)d_in[4];
    const float* A_vals  = (const float*)d_in[5];
    const int*   P1_rows = (const int*)d_in[6];
    const int*   P1_cols = (const int*)d_in[7];
    const float* P1_vals = (const float*)d_in[8];
    const int*   P2_rows = (const int*)d_in[9];
    const int*   P2_cols = (const int*)d_in[10];
    const float* P2_vals = (const float*)d_in[11];
    const int*   P3_rows = (const int*)d_in[12];
    const int*   P3_cols = (const int*)d_in[13];
    const float* P3_vals = (const float*)d_in[14];

    const size_t NF = (size_t)NN * OUTF;  // 6.4M floats

    // ---- ws: 6 dense slots (153.6 MB) + gcur; total well under 179.2 MB ----
    float* ws = (float*)d_ws;
    float* S0 = ws + NF * 0;   // support0, later hA2
    float* S1 = ws + NF * 1;   // s1
    float* S2 = ws + NF * 2;   // s2
    float* S3 = ws + NF * 3;   // s3
    float* S4 = ws + NF * 4;   // hA
    float* S5 = ws + NF * 5;   // hA3
    int* gcur = (int*)(ws + NF * 6);     // NBINS ints

    // ---- binned edge buffer lives in d_out (scratch until fuse overwrites) ----
    // NBINS * CAP * 8B = 27.98 MB <= 28.0 MB of d_out
    uint2* binned = (uint2*)d_out;

    const int GB = (EE + SBLK - 1) / SBLK;  // 196 bin_scatter blocks

    auto build = [&](const int* rows, const int* cols, const float* vals) {
        hipMemsetAsync(gcur, 0, (size_t)NBINS * sizeof(int), stream);
        bin_scatter<<<GB, 256, 0, stream>>>(rows, cols, vals, gcur, binned, EE);
    };

    gemm_kernel<<<NN / 4, 256, 0, stream>>>(x, W, S0);

    build(P1_rows, P1_cols, P1_vals);
    spmm_bin<<<NBINS, 256, 0, stream>>>(binned, gcur, S0, S1);   // s1
    build(P2_rows, P2_cols, P2_vals);
    spmm_bin<<<NBINS, 256, 0, stream>>>(binned, gcur, S0, S2);   // s2
    build(P3_rows, P3_cols, P3_vals);
    spmm_bin<<<NBINS, 256, 0, stream>>>(binned, gcur, S0, S3);   // s3
    build(A_rows, A_cols, A_vals);
    spmm_bin<<<NBINS, 256, 0, stream>>>(binned, gcur, S0, S4);   // hA (support0 dead after)
    spmm_bin<<<NBINS, 256, 0, stream>>>(binned, gcur, S4, S0);   // hA2 (reuses S0)
    spmm_bin<<<NBINS, 256, 0, stream>>>(binned, gcur, S0, S5);   // hA3

    fuse_kernel<<<(NN + 3) / 4, 256, 0, stream>>>(S4, S0, S5, S1, S2, S3, a, (float*)d_out);
}

// Round 5
// 1384.604 us; speedup vs baseline: 6.5836x; 6.5836x over previous
//
#include <hip/hip_runtime.h>
#include <math.h>

#define NN 100000
#define EE 3200000
#define INF 128
#define OUTF 64
#define ALPHA 0.1f

#define BROWS 128                      // rows per bin
#define NBINS 782                      // ceil(NN/BROWS)
#define CAP 4472                       // per-bin slot capacity (mean 4092, +5.9 sigma)
#define SCHUNK 4096                    // edges sorted per LDS chunk
#define SBLK 16384                     // edges per bin_scatter block
#define NSUM ((NBINS + 3) / 4)         // 196

// ---------------- GEMM: support0 = x @ W  ([N,128]@[128,64]) ----------------
__global__ __launch_bounds__(256) void gemm_kernel(
    const float* __restrict__ x, const float* __restrict__ W, float* __restrict__ out)
{
    __shared__ float Wl[INF * OUTF];  // 32 KB
    for (int idx = threadIdx.x; idx < INF * OUTF; idx += 256) Wl[idx] = W[idx];
    __syncthreads();

    int row = blockIdx.x * 4 + (threadIdx.x >> 6);
    int f = threadIdx.x & 63;
    if (row >= NN) return;
    const float* xr = x + (size_t)row * INF;
    float acc = 0.f;
#pragma unroll
    for (int k = 0; k < INF; k += 4) {
        float4 xv = *reinterpret_cast<const float4*>(xr + k);
        acc += xv.x * Wl[(k + 0) * OUTF + f];
        acc += xv.y * Wl[(k + 1) * OUTF + f];
        acc += xv.z * Wl[(k + 2) * OUTF + f];
        acc += xv.w * Wl[(k + 3) * OUTF + f];
    }
    out[(size_t)row * OUTF + f] = acc;
}

// ------------- binning pass: counting-sort edges into 128-row bins ----------
// Per block: histogram its 16K edges, reserve per-bin global space once
// (runs from successive 4K chunks concatenate), then per 4K chunk: LDS
// counting sort by bin + coalesced run writes.
__global__ __launch_bounds__(256) void bin_scatter(
    const int* __restrict__ rows, const int* __restrict__ cols,
    const float* __restrict__ vals, int* __restrict__ gcur,
    uint2* __restrict__ binned, int nedges)
{
    __shared__ uint2 rec[SCHUNK];          // 32 KB
    __shared__ unsigned short bin_of[SCHUNK];  // 8 KB
    __shared__ int hist[NBINS];
    __shared__ int lcur[NBINS];
    __shared__ int hc[NBINS];
    __shared__ int off[NBINS + 1];
    __shared__ int cur[NBINS];
    __shared__ int sums[NSUM];

    int tid = threadIdx.x;
    int base = blockIdx.x * SBLK;
    int n = min(SBLK, nedges - base);
    if (n <= 0) return;

    for (int b = tid; b < NBINS; b += 256) hist[b] = 0;
    __syncthreads();
    for (int i = tid; i < n; i += 256) atomicAdd(&hist[rows[base + i] >> 7], 1);
    __syncthreads();
    for (int b = tid; b < NBINS; b += 256) {
        int c = hist[b];
        lcur[b] = c ? atomicAdd(&gcur[b], c) : 0;
    }

    for (int c0 = 0; c0 < n; c0 += SCHUNK) {
        int nc = min(SCHUNK, n - c0);
        __syncthreads();
        for (int b = tid; b < NBINS; b += 256) hc[b] = 0;
        __syncthreads();
        for (int i = tid; i < nc; i += 256)
            atomicAdd(&hc[rows[base + c0 + i] >> 7], 1);
        __syncthreads();
        if (tid < NSUM) {
            int s = 0;
#pragma unroll
            for (int k = 0; k < 4; k++) { int b = 4 * tid + k; if (b < NBINS) s += hc[b]; }
            sums[tid] = s;
        }
        __syncthreads();
        if (tid == 0) {
            int acc = 0;
            for (int t = 0; t < NSUM; t++) { int v = sums[t]; sums[t] = acc; acc += v; }
            off[NBINS] = acc;
        }
        __syncthreads();
        if (tid < NSUM) {
            int acc = sums[tid];
#pragma unroll
            for (int k = 0; k < 4; k++) {
                int b = 4 * tid + k;
                if (b < NBINS) { off[b] = acc; cur[b] = acc; acc += hc[b]; }
            }
        }
        __syncthreads();
        // place records sorted-by-bin into rec (remember each slot's bin)
        for (int i = tid; i < nc; i += 256) {
            int r = rows[base + c0 + i];
            int cc = cols[base + c0 + i];
            float v = vals[base + c0 + i];
            int b = r >> 7;
            int pos = atomicAdd(&cur[b], 1);
            uint2 q;
            q.x = (unsigned)cc | ((unsigned)(r & (BROWS - 1)) << 17);
            q.y = __float_as_uint(v);
            rec[pos] = q;
            bin_of[pos] = (unsigned short)b;
        }
        __syncthreads();
        // run writes: consecutive i -> consecutive global dest within a run
        for (int i = tid; i < nc; i += 256) {
            int b = bin_of[i];
            int slot = lcur[b] + (i - off[b]);
            if (slot < CAP) binned[(size_t)b * CAP + slot] = rec[i];
        }
        __syncthreads();
        for (int b = tid; b < NBINS; b += 256) lcur[b] += hc[b];
    }
}

// ------------- per-bin counting sort by local row (in place) + rowptr/cnt ---
__global__ __launch_bounds__(256) void bin_sort(
    uint2* __restrict__ binned, const int* __restrict__ gcur,
    int* __restrict__ rowptr, int* __restrict__ cnt)
{
    __shared__ uint2 rin[CAP];    // 35.8 KB
    __shared__ uint2 rout[CAP];   // 35.8 KB
    __shared__ int h[BROWS], hs[BROWS], cur[BROWS];

    int bin = blockIdx.x;
    int tid = threadIdx.x;
    int c = min(gcur[bin], CAP);
    uint2* src = binned + (size_t)bin * CAP;

    for (int i = tid; i < c; i += 256) rin[i] = src[i];
    if (tid < BROWS) { h[tid] = 0; }
    __syncthreads();
    for (int i = tid; i < c; i += 256)
        atomicAdd(&h[(rin[i].x >> 17) & (BROWS - 1)], 1);
    __syncthreads();
    if (tid < BROWS) hs[tid] = h[tid];
    __syncthreads();
#pragma unroll
    for (int o = 1; o < BROWS; o <<= 1) {
        int w = (tid >= o && tid < BROWS) ? hs[tid - o] : 0;
        __syncthreads();
        if (tid < BROWS) hs[tid] += w;
        __syncthreads();
    }
    if (tid < BROWS) cur[tid] = hs[tid] - h[tid];   // exclusive
    __syncthreads();
    for (int i = tid; i < c; i += 256) {
        uint2 q = rin[i];
        int pos = atomicAdd(&cur[(q.x >> 17) & (BROWS - 1)], 1);
        rout[pos] = q;
    }
    __syncthreads();
    for (int i = tid; i < c; i += 256) src[i] = rout[i];

    if (tid < BROWS) {
        int gr = bin * BROWS + tid;
        if (gr < NN) {
            rowptr[gr] = bin * CAP + (hs[tid] - h[tid]);
            cnt[gr] = h[tid];
        }
    }
}

// ---------------- SpMM (padded CSR gather-reduce): one wave per row ---------
__global__ __launch_bounds__(256) void spmm_csr(
    const int* __restrict__ rowptr, const int* __restrict__ cnt,
    const uint2* __restrict__ edges,
    const float* __restrict__ X, float* __restrict__ Y)
{
    int row = blockIdx.x * 4 + (threadIdx.x >> 6);
    int lane = threadIdx.x & 63;
    if (row >= NN) return;
    int s = rowptr[row];
    int e = s + cnt[row];
    float acc = 0.f;
    int i = s;
    for (; i + 7 < e; i += 8) {
        uint2 p0 = edges[i + 0], p1 = edges[i + 1], p2 = edges[i + 2], p3 = edges[i + 3];
        uint2 p4 = edges[i + 4], p5 = edges[i + 5], p6 = edges[i + 6], p7 = edges[i + 7];
        float x0 = X[(size_t)(p0.x & 0x1FFFF) * OUTF + lane];
        float x1 = X[(size_t)(p1.x & 0x1FFFF) * OUTF + lane];
        float x2 = X[(size_t)(p2.x & 0x1FFFF) * OUTF + lane];
        float x3 = X[(size_t)(p3.x & 0x1FFFF) * OUTF + lane];
        float x4 = X[(size_t)(p4.x & 0x1FFFF) * OUTF + lane];
        float x5 = X[(size_t)(p5.x & 0x1FFFF) * OUTF + lane];
        float x6 = X[(size_t)(p6.x & 0x1FFFF) * OUTF + lane];
        float x7 = X[(size_t)(p7.x & 0x1FFFF) * OUTF + lane];
        acc += __uint_as_float(p0.y) * x0;
        acc += __uint_as_float(p1.y) * x1;
        acc += __uint_as_float(p2.y) * x2;
        acc += __uint_as_float(p3.y) * x3;
        acc += __uint_as_float(p4.y) * x4;
        acc += __uint_as_float(p5.y) * x5;
        acc += __uint_as_float(p6.y) * x6;
        acc += __uint_as_float(p7.y) * x7;
    }
    for (; i < e; i++) {
        uint2 p = edges[i];
        acc += __uint_as_float(p.y) * X[(size_t)(p.x & 0x1FFFF) * OUTF + lane];
    }
    Y[(size_t)row * OUTF + lane] = acc;
}

// ---------------- Fused attention epilogue ----------------------------------
__global__ __launch_bounds__(256) void fuse_kernel(
    const float* __restrict__ hA, const float* __restrict__ hA2, const float* __restrict__ hA3,
    const float* __restrict__ s1, const float* __restrict__ s2, const float* __restrict__ s3,
    const float* __restrict__ a, float* __restrict__ out)
{
    __shared__ float chl[4][6][OUTF];  // 6 KB
    int wid = threadIdx.x >> 6;
    int lane = threadIdx.x & 63;
    int i = blockIdx.x * 4 + wid;
    if (i >= NN) return;

    const float* bufs[6] = {hA, hA2, hA3, s1, s2, s3};

#pragma unroll
    for (int k = 0; k < 6; k++) {
        float v = bufs[k][(size_t)i * OUTF + lane];
        if (k >= 3) v = fabsf(v);
        chl[wid][k][lane] = v;
    }

    float att[6];
    if (i < NN / 2) {
#pragma unroll
        for (int k = 0; k < 6; k++) att[k] = 1.0f / 6.0f;
    } else {
        int m = 2 * i - NN;
        float alo = a[lane];
        float ahi = a[64 + lane];
        float e[6];
#pragma unroll
        for (int k = 0; k < 6; k++) {
            float v0 = bufs[k][(size_t)m * OUTF + lane];
            float v1 = bufs[k][(size_t)(m + 1) * OUTF + lane];
            if (k >= 3) { v0 = fabsf(v0); v1 = fabsf(v1); }
            float p = alo * v0 + ahi * v1;
#pragma unroll
            for (int off = 32; off; off >>= 1) p += __shfl_xor(p, off);
            e[k] = (p > 0.f) ? p : ALPHA * p;
        }
        float mx = e[0];
#pragma unroll
        for (int k = 1; k < 6; k++) mx = fmaxf(mx, e[k]);
        float s = 0.f;
#pragma unroll
        for (int k = 0; k < 6; k++) { att[k] = __expf(e[k] - mx); s += att[k]; }
        float inv = 1.f / s;
#pragma unroll
        for (int k = 0; k < 6; k++) att[k] *= inv;
    }

    if (lane < 6) out[(size_t)NN * OUTF + (size_t)i * 6 + lane] = att[lane];

    float hp = 0.f;
#pragma unroll
    for (int j = 0; j < 6; j++) {
        int g = j * 64 + lane;
        hp += att[j] * chl[wid][g % 6][g / 6];
    }
    out[(size_t)i * OUTF + lane] = hp * (1.0f / 6.0f);
}

extern "C" void kernel_launch(void* const* d_in, const int* in_sizes, int n_in,
                              void* d_out, int out_size, void* d_ws, size_t ws_size,
                              hipStream_t stream)
{
    const float* x = (const float*)d_in[0];
    const float* W = (const float*)d_in[1];
    const float* a = (const float*)d_in[2];
    const int*   A_rows  = (const int*)d_in[3];
    const int*   A_cols  = (const int*)d_in[4];
    const float* A_vals  = (const float*)d_in[5];
    const int*   P1_rows = (const int*)d_in[6];
    const int*   P1_cols = (const int*)d_in[7];
    const float* P1_vals = (const float*)d_in[8];
    const int*   P2_rows = (const int*)d_in[9];
    const int*   P2_cols = (const int*)d_in[10];
    const float* P2_vals = (const float*)d_in[11];
    const int*   P3_rows = (const int*)d_in[12];
    const int*   P3_cols = (const int*)d_in[13];
    const float* P3_vals = (const float*)d_in[14];

    const size_t NF = (size_t)NN * OUTF;  // 6.4M floats

    // ---- ws: 6 dense slots (153.6 MB) + CSR metadata (~0.8 MB) ----
    float* ws = (float*)d_ws;
    float* S0 = ws + NF * 0;   // support0, later hA2
    float* S1 = ws + NF * 1;   // s1
    float* S2 = ws + NF * 2;   // s2
    float* S3 = ws + NF * 3;   // s3
    float* S4 = ws + NF * 4;   // hA
    float* S5 = ws + NF * 5;   // hA3
    int* gcur   = (int*)(ws + NF * 6);          // NBINS
    int* rowptr = gcur + NBINS;                 // NN
    int* cnt    = rowptr + NN;                  // NN

    // binned edge buffer in d_out (scratch until fuse fully overwrites it):
    // NBINS*CAP*8B = 27.977 MB <= 28.0 MB
    uint2* binned = (uint2*)d_out;

    const int GB = (EE + SBLK - 1) / SBLK;  // 196
    const int RB = (NN + 3) / 4;            // 25000

    auto build = [&](const int* rows, const int* cols, const float* vals) {
        hipMemsetAsync(gcur, 0, (size_t)NBINS * sizeof(int), stream);
        bin_scatter<<<GB, 256, 0, stream>>>(rows, cols, vals, gcur, binned, EE);
        bin_sort<<<NBINS, 256, 0, stream>>>(binned, gcur, rowptr, cnt);
    };

    gemm_kernel<<<NN / 4, 256, 0, stream>>>(x, W, S0);

    build(P1_rows, P1_cols, P1_vals);
    spmm_csr<<<RB, 256, 0, stream>>>(rowptr, cnt, binned, S0, S1);   // s1
    build(P2_rows, P2_cols, P2_vals);
    spmm_csr<<<RB, 256, 0, stream>>>(rowptr, cnt, binned, S0, S2);   // s2
    build(P3_rows, P3_cols, P3_vals);
    spmm_csr<<<RB, 256, 0, stream>>>(rowptr, cnt, binned, S0, S3);   // s3
    build(A_rows, A_cols, A_vals);
    spmm_csr<<<RB, 256, 0, stream>>>(rowptr, cnt, binned, S0, S4);   // hA
    spmm_csr<<<RB, 256, 0, stream>>>(rowptr, cnt, binned, S4, S0);   // hA2 (support0 dead)
    spmm_csr<<<RB, 256, 0, stream>>>(rowptr, cnt, binned, S0, S5);   // hA3

    fuse_kernel<<<RB, 256, 0, stream>>>(S4, S0, S5, S1, S2, S3, a, (float*)d_out);
}

// Round 6
// 1292.777 us; speedup vs baseline: 7.0512x; 1.0710x over previous
//
#include <hip/hip_runtime.h>
#include <math.h>

#define NN 100000
#define EE 3200000
#define INF 128
#define OUTF 64
#define ALPHA 0.1f

#define BROWS 128                      // rows per bin
#define NBINS 782                      // ceil(NN/BROWS)
#define CAP 4472                       // per-bin slot capacity (mean 4092, +5.9 sigma)
#define SCHUNK 4096                    // edges sorted per LDS chunk
#define SBLK 16384                     // edges per bin_scatter block
#define NSUM ((NBINS + 3) / 4)         // 196

#define GR 64                          // gemm rows per block
#define XPAD 132                       // x-tile row stride (floats): conflict-free + 16B aligned

// ---------------- GEMM: support0 = x @ W  ([N,128]@[128,64]) ----------------
// 4x4 register tile per thread; block = 64 rows x 64 cols.
__global__ __launch_bounds__(256) void gemm_kernel(
    const float* __restrict__ x, const float* __restrict__ W, float* __restrict__ out)
{
    __shared__ float Wl[INF * OUTF];       // 32 KB, row-major [128][64]
    __shared__ float xL[GR * XPAD];        // 33.8 KB, [row][k] padded

    int tid = threadIdx.x;
    int tx = tid & 15;          // col group: cols 4*tx .. 4*tx+3
    int ty = tid >> 4;          // row group: rows 4*ty .. 4*ty+3
    int r0 = blockIdx.x * GR;

    // stage W (coalesced float4)
    const float4* W4 = (const float4*)W;
    float4* Wl4 = (float4*)Wl;
    for (int i = tid; i < INF * OUTF / 4; i += 256) Wl4[i] = W4[i];

    // stage x tile: read row-major coalesced float4, write b128 into padded rows
    for (int i = tid; i < GR * (INF / 4); i += 256) {
        int row = i >> 5;                    // 0..63
        int c4 = i & 31;                     // 0..31 (k = 4*c4)
        int gr = r0 + row;
        float4 v = make_float4(0.f, 0.f, 0.f, 0.f);
        if (gr < NN) v = *(const float4*)&x[(size_t)gr * INF + 4 * c4];
        *(float4*)&xL[row * XPAD + 4 * c4] = v;
    }
    __syncthreads();

    float acc[4][4];
#pragma unroll
    for (int i = 0; i < 4; i++)
#pragma unroll
        for (int j = 0; j < 4; j++) acc[i][j] = 0.f;

#pragma unroll 4
    for (int k4 = 0; k4 < INF / 4; k4++) {
        float4 xv[4], wv[4];
#pragma unroll
        for (int i = 0; i < 4; i++)
            xv[i] = *(float4*)&xL[(4 * ty + i) * XPAD + 4 * k4];
#pragma unroll
        for (int kk = 0; kk < 4; kk++)
            wv[kk] = *(float4*)&Wl[(4 * k4 + kk) * OUTF + 4 * tx];
#pragma unroll
        for (int i = 0; i < 4; i++) {
#pragma unroll
            for (int kk = 0; kk < 4; kk++) {
                acc[i][0] = fmaf(((float*)&xv[i])[kk], ((float*)&wv[kk])[0], acc[i][0]);
                acc[i][1] = fmaf(((float*)&xv[i])[kk], ((float*)&wv[kk])[1], acc[i][1]);
                acc[i][2] = fmaf(((float*)&xv[i])[kk], ((float*)&wv[kk])[2], acc[i][2]);
                acc[i][3] = fmaf(((float*)&xv[i])[kk], ((float*)&wv[kk])[3], acc[i][3]);
            }
        }
    }

#pragma unroll
    for (int i = 0; i < 4; i++) {
        int gr = r0 + 4 * ty + i;
        if (gr < NN) {
            float4 o;
            o.x = acc[i][0]; o.y = acc[i][1]; o.z = acc[i][2]; o.w = acc[i][3];
            *(float4*)&out[(size_t)gr * OUTF + 4 * tx] = o;
        }
    }
}

// ------------- binning pass: counting-sort edges into 128-row bins ----------
__global__ __launch_bounds__(256) void bin_scatter(
    const int* __restrict__ rows, const int* __restrict__ cols,
    const float* __restrict__ vals, int* __restrict__ gcur,
    uint2* __restrict__ binned, int nedges)
{
    __shared__ uint2 rec[SCHUNK];          // 32 KB
    __shared__ unsigned short bin_of[SCHUNK];  // 8 KB
    __shared__ int hist[NBINS];
    __shared__ int lcur[NBINS];
    __shared__ int hc[NBINS];
    __shared__ int off[NBINS + 1];
    __shared__ int cur[NBINS];
    __shared__ int sums[NSUM];

    int tid = threadIdx.x;
    int base = blockIdx.x * SBLK;
    int n = min(SBLK, nedges - base);
    if (n <= 0) return;

    for (int b = tid; b < NBINS; b += 256) hist[b] = 0;
    __syncthreads();
    for (int i = tid; i < n; i += 256) atomicAdd(&hist[rows[base + i] >> 7], 1);
    __syncthreads();
    for (int b = tid; b < NBINS; b += 256) {
        int c = hist[b];
        lcur[b] = c ? atomicAdd(&gcur[b], c) : 0;
    }

    for (int c0 = 0; c0 < n; c0 += SCHUNK) {
        int nc = min(SCHUNK, n - c0);
        __syncthreads();
        for (int b = tid; b < NBINS; b += 256) hc[b] = 0;
        __syncthreads();
        for (int i = tid; i < nc; i += 256)
            atomicAdd(&hc[rows[base + c0 + i] >> 7], 1);
        __syncthreads();
        if (tid < NSUM) {
            int s = 0;
#pragma unroll
            for (int k = 0; k < 4; k++) { int b = 4 * tid + k; if (b < NBINS) s += hc[b]; }
            sums[tid] = s;
        }
        __syncthreads();
        if (tid == 0) {
            int acc = 0;
            for (int t = 0; t < NSUM; t++) { int v = sums[t]; sums[t] = acc; acc += v; }
            off[NBINS] = acc;
        }
        __syncthreads();
        if (tid < NSUM) {
            int acc = sums[tid];
#pragma unroll
            for (int k = 0; k < 4; k++) {
                int b = 4 * tid + k;
                if (b < NBINS) { off[b] = acc; cur[b] = acc; acc += hc[b]; }
            }
        }
        __syncthreads();
        for (int i = tid; i < nc; i += 256) {
            int r = rows[base + c0 + i];
            int cc = cols[base + c0 + i];
            float v = vals[base + c0 + i];
            int b = r >> 7;
            int pos = atomicAdd(&cur[b], 1);
            uint2 q;
            q.x = (unsigned)cc | ((unsigned)(r & (BROWS - 1)) << 17);
            q.y = __float_as_uint(v);
            rec[pos] = q;
            bin_of[pos] = (unsigned short)b;
        }
        __syncthreads();
        for (int i = tid; i < nc; i += 256) {
            int b = bin_of[i];
            int slot = lcur[b] + (i - off[b]);
            if (slot < CAP) binned[(size_t)b * CAP + slot] = rec[i];
        }
        __syncthreads();
        for (int b = tid; b < NBINS; b += 256) lcur[b] += hc[b];
    }
}

// ------------- per-bin counting sort by local row (in place) + rowptr/cnt ---
__global__ __launch_bounds__(256) void bin_sort(
    uint2* __restrict__ binned, const int* __restrict__ gcur,
    int* __restrict__ rowptr, int* __restrict__ cnt)
{
    __shared__ uint2 rin[CAP];    // 35.8 KB
    __shared__ uint2 rout[CAP];   // 35.8 KB
    __shared__ int h[BROWS], hs[BROWS], cur[BROWS];

    int bin = blockIdx.x;
    int tid = threadIdx.x;
    int c = min(gcur[bin], CAP);
    uint2* src = binned + (size_t)bin * CAP;

    for (int i = tid; i < c; i += 256) rin[i] = src[i];
    if (tid < BROWS) { h[tid] = 0; }
    __syncthreads();
    for (int i = tid; i < c; i += 256)
        atomicAdd(&h[(rin[i].x >> 17) & (BROWS - 1)], 1);
    __syncthreads();
    if (tid < BROWS) hs[tid] = h[tid];
    __syncthreads();
#pragma unroll
    for (int o = 1; o < BROWS; o <<= 1) {
        int w = (tid >= o && tid < BROWS) ? hs[tid - o] : 0;
        __syncthreads();
        if (tid < BROWS) hs[tid] += w;
        __syncthreads();
    }
    if (tid < BROWS) cur[tid] = hs[tid] - h[tid];   // exclusive
    __syncthreads();
    for (int i = tid; i < c; i += 256) {
        uint2 q = rin[i];
        int pos = atomicAdd(&cur[(q.x >> 17) & (BROWS - 1)], 1);
        rout[pos] = q;
    }
    __syncthreads();
    for (int i = tid; i < c; i += 256) src[i] = rout[i];

    if (tid < BROWS) {
        int gr = bin * BROWS + tid;
        if (gr < NN) {
            rowptr[gr] = bin * CAP + (hs[tid] - h[tid]);
            cnt[gr] = h[tid];
        }
    }
}

// ---------------- SpMM (padded CSR gather-reduce): one wave per row ---------
__global__ __launch_bounds__(256) void spmm_csr(
    const int* __restrict__ rowptr, const int* __restrict__ cnt,
    const uint2* __restrict__ edges,
    const float* __restrict__ X, float* __restrict__ Y)
{
    int row = blockIdx.x * 4 + (threadIdx.x >> 6);
    int lane = threadIdx.x & 63;
    if (row >= NN) return;
    int s = rowptr[row];
    int e = s + cnt[row];
    float acc = 0.f;
    int i = s;
    for (; i + 7 < e; i += 8) {
        uint2 p0 = edges[i + 0], p1 = edges[i + 1], p2 = edges[i + 2], p3 = edges[i + 3];
        uint2 p4 = edges[i + 4], p5 = edges[i + 5], p6 = edges[i + 6], p7 = edges[i + 7];
        float x0 = X[(size_t)(p0.x & 0x1FFFF) * OUTF + lane];
        float x1 = X[(size_t)(p1.x & 0x1FFFF) * OUTF + lane];
        float x2 = X[(size_t)(p2.x & 0x1FFFF) * OUTF + lane];
        float x3 = X[(size_t)(p3.x & 0x1FFFF) * OUTF + lane];
        float x4 = X[(size_t)(p4.x & 0x1FFFF) * OUTF + lane];
        float x5 = X[(size_t)(p5.x & 0x1FFFF) * OUTF + lane];
        float x6 = X[(size_t)(p6.x & 0x1FFFF) * OUTF + lane];
        float x7 = X[(size_t)(p7.x & 0x1FFFF) * OUTF + lane];
        acc += __uint_as_float(p0.y) * x0;
        acc += __uint_as_float(p1.y) * x1;
        acc += __uint_as_float(p2.y) * x2;
        acc += __uint_as_float(p3.y) * x3;
        acc += __uint_as_float(p4.y) * x4;
        acc += __uint_as_float(p5.y) * x5;
        acc += __uint_as_float(p6.y) * x6;
        acc += __uint_as_float(p7.y) * x7;
    }
    for (; i < e; i++) {
        uint2 p = edges[i];
        acc += __uint_as_float(p.y) * X[(size_t)(p.x & 0x1FFFF) * OUTF + lane];
    }
    Y[(size_t)row * OUTF + lane] = acc;
}

// ---------------- Fused attention epilogue ----------------------------------
__global__ __launch_bounds__(256) void fuse_kernel(
    const float* __restrict__ hA, const float* __restrict__ hA2, const float* __restrict__ hA3,
    const float* __restrict__ s1, const float* __restrict__ s2, const float* __restrict__ s3,
    const float* __restrict__ a, float* __restrict__ out)
{
    __shared__ float chl[4][6][OUTF];  // 6 KB
    int wid = threadIdx.x >> 6;
    int lane = threadIdx.x & 63;
    int i = blockIdx.x * 4 + wid;
    if (i >= NN) return;

    const float* bufs[6] = {hA, hA2, hA3, s1, s2, s3};

#pragma unroll
    for (int k = 0; k < 6; k++) {
        float v = bufs[k][(size_t)i * OUTF + lane];
        if (k >= 3) v = fabsf(v);
        chl[wid][k][lane] = v;
    }

    float att[6];
    if (i < NN / 2) {
#pragma unroll
        for (int k = 0; k < 6; k++) att[k] = 1.0f / 6.0f;
    } else {
        int m = 2 * i - NN;
        float alo = a[lane];
        float ahi = a[64 + lane];
        float e[6];
#pragma unroll
        for (int k = 0; k < 6; k++) {
            float v0 = bufs[k][(size_t)m * OUTF + lane];
            float v1 = bufs[k][(size_t)(m + 1) * OUTF + lane];
            if (k >= 3) { v0 = fabsf(v0); v1 = fabsf(v1); }
            float p = alo * v0 + ahi * v1;
#pragma unroll
            for (int off = 32; off; off >>= 1) p += __shfl_xor(p, off);
            e[k] = (p > 0.f) ? p : ALPHA * p;
        }
        float mx = e[0];
#pragma unroll
        for (int k = 1; k < 6; k++) mx = fmaxf(mx, e[k]);
        float s = 0.f;
#pragma unroll
        for (int k = 0; k < 6; k++) { att[k] = __expf(e[k] - mx); s += att[k]; }
        float inv = 1.f / s;
#pragma unroll
        for (int k = 0; k < 6; k++) att[k] *= inv;
    }

    if (lane < 6) out[(size_t)NN * OUTF + (size_t)i * 6 + lane] = att[lane];

    float hp = 0.f;
#pragma unroll
    for (int j = 0; j < 6; j++) {
        int g = j * 64 + lane;
        hp += att[j] * chl[wid][g % 6][g / 6];
    }
    out[(size_t)i * OUTF + lane] = hp * (1.0f / 6.0f);
}

extern "C" void kernel_launch(void* const* d_in, const int* in_sizes, int n_in,
                              void* d_out, int out_size, void* d_ws, size_t ws_size,
                              hipStream_t stream)
{
    const float* x = (const float*)d_in[0];
    const float* W = (const float*)d_in[1];
    const float* a = (const float*)d_in[2];
    const int*   A_rows  = (const int*)d_in[3];
    const int*   A_cols  = (const int*)d_in[4];
    const float* A_vals  = (const float*)d_in[5];
    const int*   P1_rows = (const int*)d_in[6];
    const int*   P1_cols = (const int*)d_in[7];
    const float* P1_vals = (const float*)d_in[8];
    const int*   P2_rows = (const int*)d_in[9];
    const int*   P2_cols = (const int*)d_in[10];
    const float* P2_vals = (const float*)d_in[11];
    const int*   P3_rows = (const int*)d_in[12];
    const int*   P3_cols = (const int*)d_in[13];
    const float* P3_vals = (const float*)d_in[14];

    const size_t NF = (size_t)NN * OUTF;  // 6.4M floats

    // ---- ws: 6 dense slots (153.6 MB) + CSR metadata (~0.8 MB) ----
    float* ws = (float*)d_ws;
    float* S0 = ws + NF * 0;   // support0, later hA2
    float* S1 = ws + NF * 1;   // s1
    float* S2 = ws + NF * 2;   // s2
    float* S3 = ws + NF * 3;   // s3
    float* S4 = ws + NF * 4;   // hA
    float* S5 = ws + NF * 5;   // hA3
    int* gcur   = (int*)(ws + NF * 6);          // NBINS
    int* rowptr = gcur + NBINS;                 // NN
    int* cnt    = rowptr + NN;                  // NN

    // binned edge buffer in d_out (scratch until fuse fully overwrites it):
    // NBINS*CAP*8B = 27.977 MB <= 28.0 MB
    uint2* binned = (uint2*)d_out;

    const int GB = (EE + SBLK - 1) / SBLK;  // 196
    const int RB = (NN + 3) / 4;            // 25000

    auto build = [&](const int* rows, const int* cols, const float* vals) {
        hipMemsetAsync(gcur, 0, (size_t)NBINS * sizeof(int), stream);
        bin_scatter<<<GB, 256, 0, stream>>>(rows, cols, vals, gcur, binned, EE);
        bin_sort<<<NBINS, 256, 0, stream>>>(binned, gcur, rowptr, cnt);
    };

    gemm_kernel<<<(NN + GR - 1) / GR, 256, 0, stream>>>(x, W, S0);

    build(P1_rows, P1_cols, P1_vals);
    spmm_csr<<<RB, 256, 0, stream>>>(rowptr, cnt, binned, S0, S1);   // s1
    build(P2_rows, P2_cols, P2_vals);
    spmm_csr<<<RB, 256, 0, stream>>>(rowptr, cnt, binned, S0, S2);   // s2
    build(P3_rows, P3_cols, P3_vals);
    spmm_csr<<<RB, 256, 0, stream>>>(rowptr, cnt, binned, S0, S3);   // s3
    build(A_rows, A_cols, A_vals);
    spmm_csr<<<RB, 256, 0, stream>>>(rowptr, cnt, binned, S0, S4);   // hA
    spmm_csr<<<RB, 256, 0, stream>>>(rowptr, cnt, binned, S4, S0);   // hA2 (support0 dead)
    spmm_csr<<<RB, 256, 0, stream>>>(rowptr, cnt, binned, S0, S5);   // hA3

    fuse_kernel<<<RB, 256, 0, stream>>>(S4, S0, S5, S1, S2, S3, a, (float*)d_out);
}